// Round 1
// baseline (2999.024 us; speedup 1.0000x reference)
//
#include <hip/hip_runtime.h>
#include <hip/hip_bf16.h>

typedef __attribute__((ext_vector_type(8))) unsigned short u16x8;

#define DEVI __device__ __forceinline__

constexpr int Bc = 16;
constexpr int Nc = 4096;
constexpr int Sc = 1024;   // NPOINT
constexpr int Kc = 32;
constexpr int Dc = 64;
constexpr int C1 = 67;
constexpr int Mtot = Bc * Sc * Kc;  // 524288
constexpr float EPSc = 1e-5f;
constexpr float CNTinv = 1.0f / (float)Mtot;

// no-FMA squared distance, matches numpy (x*x + y*y) + z*z
DEVI float sqdist3(float dx, float dy, float dz) {
  return __fadd_rn(__fadd_rn(__fmul_rn(dx, dx), __fmul_rn(dy, dy)), __fmul_rn(dz, dz));
}
DEVI unsigned long long umax64(unsigned long long a, unsigned long long b) { return a > b ? a : b; }
DEVI unsigned long long umin64(unsigned long long a, unsigned long long b) { return a < b ? a : b; }
DEVI float bf2f(unsigned short u) { return __uint_as_float(((unsigned)u) << 16); }
DEVI unsigned pack_bf2(float a, float b) {
  __hip_bfloat16 ha = __float2bfloat16(a), hb = __float2bfloat16(b);
  unsigned short ua, ub;
  __builtin_memcpy(&ua, &ha, 2);
  __builtin_memcpy(&ub, &hb, 2);
  return (unsigned)ua | ((unsigned)ub << 16);
}

// ---------------- FPS: one block per batch, dist+coords in registers ----------------
__global__ __launch_bounds__(512) void fps_kernel(const float* __restrict__ xyz,
                                                  int* __restrict__ fidx) {
  const int b = blockIdx.x;
  const float* xb = xyz + (size_t)b * Nc * 3;
  const int tid = threadIdx.x;
  float px[8], py[8], pz[8], dist[8];
#pragma unroll
  for (int i = 0; i < 8; ++i) {
    int p = tid + i * 512;
    px[i] = xb[p * 3 + 0];
    py[i] = xb[p * 3 + 1];
    pz[i] = xb[p * 3 + 2];
    dist[i] = 1e10f;
  }
  __shared__ unsigned long long wmax[8];
  __shared__ float cent[3];
  if (tid == 0) {
    fidx[b * Sc] = 0;
    cent[0] = xb[0];
    cent[1] = xb[1];
    cent[2] = xb[2];
  }
  __syncthreads();
  for (int t = 1; t < Sc; ++t) {
    const float cx = cent[0], cy = cent[1], cz = cent[2];
    unsigned long long best = 0ull;
#pragma unroll
    for (int i = 0; i < 8; ++i) {
      float d = sqdist3(px[i] - cx, py[i] - cy, pz[i] - cz);
      float nd = fminf(dist[i], d);
      dist[i] = nd;
      unsigned long long key = ((unsigned long long)__float_as_uint(nd) << 32) |
                               (unsigned)(0xFFFFFFFFu - (unsigned)(tid + i * 512));
      best = umax64(best, key);
    }
#pragma unroll
    for (int off = 32; off > 0; off >>= 1) {
      unsigned long long o = __shfl_xor(best, off, 64);
      best = umax64(best, o);
    }
    if ((tid & 63) == 0) wmax[tid >> 6] = best;
    __syncthreads();
    unsigned long long m = wmax[0];
#pragma unroll
    for (int wI = 1; wI < 8; ++wI) m = umax64(m, wmax[wI]);
    const int widx = (int)(0xFFFFFFFFu - (unsigned)(m & 0xFFFFFFFFu));
    if (tid == 0) fidx[b * Sc + t] = widx;
    const int rel = widx - tid;
#pragma unroll
    for (int i = 0; i < 8; ++i) {
      if (rel == i * 512) {
        cent[0] = px[i];
        cent[1] = py[i];
        cent[2] = pz[i];
      }
    }
    __syncthreads();
  }
}

// ---------------- kNN: one wave per query, LDS distance array, 32 argmin rounds ----------------
__global__ __launch_bounds__(256) void knn_kernel(const float* __restrict__ xyz,
                                                  const int* __restrict__ fidx,
                                                  float* __restrict__ new_xyz,
                                                  int* __restrict__ idx) {
  __shared__ float dls[4][Nc];  // 64 KiB
  const int w = threadIdx.x >> 6;
  const int lane = threadIdx.x & 63;
  const int q = blockIdx.x * 4 + w;
  const int b = q >> 10;
  const int s = q & (Sc - 1);
  const float* xb = xyz + (size_t)b * Nc * 3;
  const int ci = fidx[b * Sc + s];
  const float cx = xb[ci * 3 + 0], cy = xb[ci * 3 + 1], cz = xb[ci * 3 + 2];
  if (lane == 0) {
    new_xyz[(b * Sc + s) * 3 + 0] = cx;
    new_xyz[(b * Sc + s) * 3 + 1] = cy;
    new_xyz[(b * Sc + s) * 3 + 2] = cz;
  }
  float* dl = dls[w];
  for (int j = lane; j < Nc; j += 64) {
    dl[j] = sqdist3(xb[j * 3 + 0] - cx, xb[j * 3 + 1] - cy, xb[j * 3 + 2] - cz);
  }
  int* outp = idx + ((size_t)b * Sc + s) * Kc;
  for (int r = 0; r < Kc; ++r) {
    unsigned long long best = ~0ull;
    for (int j = lane; j < Nc; j += 64) {
      unsigned long long key = ((unsigned long long)__float_as_uint(dl[j]) << 32) | (unsigned)j;
      best = umin64(best, key);
    }
#pragma unroll
    for (int off = 32; off > 0; off >>= 1) {
      unsigned long long o = __shfl_xor(best, off, 64);
      best = umin64(best, o);
    }
    const unsigned wj = (unsigned)(best & 0xFFFFFFFFu);
    if (lane == (int)(wj & 63u)) dl[wj] = __uint_as_float(0x7F800000u);  // +inf
    if (lane == 0) outp[r] = (int)wj;
  }
}

// ---------------- conv1: gather (3 xyz-diff + 64 point feats) -> 64 channels ----------------
__global__ __launch_bounds__(256) void conv1_kernel(
    const float* __restrict__ xyz, const float* __restrict__ points,
    const float* __restrict__ new_xyz, const int* __restrict__ idx,
    const float* __restrict__ W1, const float* __restrict__ b1,
    __hip_bfloat16* __restrict__ x1) {
  __shared__ float feats[C1][68];
  __shared__ float Wt[C1][64];
  const int tid = threadIdx.x;
  const int m0 = blockIdx.x * 64;
  for (int e = tid; e < 64 * C1; e += 256) {
    int c = e / C1, j = e % C1;
    Wt[j][c] = W1[e];
  }
  {
    const int p = tid >> 2, qd = tid & 3;
    const int m = m0 + p;
    const int b = m >> 15;             // /(S*K)
    const int s = (m >> 5) & (Sc - 1); // (m/K)%S
    const int i = idx[m];
    const float* pr = points + ((size_t)b * Nc + i) * Dc + qd * 16;
    float4 v0 = *(const float4*)(pr + 0);
    float4 v1 = *(const float4*)(pr + 4);
    float4 v2 = *(const float4*)(pr + 8);
    float4 v3 = *(const float4*)(pr + 12);
    float vv[16] = {v0.x, v0.y, v0.z, v0.w, v1.x, v1.y, v1.z, v1.w,
                    v2.x, v2.y, v2.z, v2.w, v3.x, v3.y, v3.z, v3.w};
    const int j0 = 3 + qd * 16;
#pragma unroll
    for (int u = 0; u < 16; ++u) feats[j0 + u][p] = vv[u];
    if (qd == 0) {
      const float* xp = xyz + ((size_t)b * Nc + i) * 3;
      const float* cp = new_xyz + ((size_t)b * Sc + s) * 3;
      feats[0][p] = xp[0] - cp[0];
      feats[1][p] = xp[1] - cp[1];
      feats[2][p] = xp[2] - cp[2];
    }
  }
  __syncthreads();
  const int c0 = (tid & 15) * 4, p0 = (tid >> 4) * 4;
  float acc[4][4];
#pragma unroll
  for (int cc = 0; cc < 4; ++cc) {
    float bb = b1[c0 + cc];
#pragma unroll
    for (int pp = 0; pp < 4; ++pp) acc[pp][cc] = bb;
  }
#pragma unroll 4
  for (int j = 0; j < C1; ++j) {
    const float4 f = *(const float4*)&feats[j][p0];
    const float4 wv = *(const float4*)&Wt[j][c0];
    const float fa[4] = {f.x, f.y, f.z, f.w};
    const float wa[4] = {wv.x, wv.y, wv.z, wv.w};
#pragma unroll
    for (int pp = 0; pp < 4; ++pp)
#pragma unroll
      for (int cc = 0; cc < 4; ++cc) acc[pp][cc] = fmaf(fa[pp], wa[cc], acc[pp][cc]);
  }
#pragma unroll
  for (int pp = 0; pp < 4; ++pp) {
    unsigned r0 = pack_bf2(acc[pp][0], acc[pp][1]);
    unsigned r1 = pack_bf2(acc[pp][2], acc[pp][3]);
    unsigned short* dst = (unsigned short*)x1 + (size_t)(m0 + p0 + pp) * 64 + c0;
    *(uint2*)dst = make_uint2(r0, r1);
  }
}

// ---------------- convN: BN(prev)+ReLU on input, then 64 -> COUT conv ----------------
template <int COUT>
__global__ __launch_bounds__(256) void convN_kernel(
    const __hip_bfloat16* __restrict__ xin, const float* __restrict__ stats,
    const float* __restrict__ gamma, const float* __restrict__ beta,
    const float* __restrict__ W, const float* __restrict__ bias,
    __hip_bfloat16* __restrict__ xout) {
  constexpr int CB = COUT / 16;
  __shared__ float feats[64][68];
  __shared__ float Wt[64][COUT];
  __shared__ float scs[64], shs[64];
  const int tid = threadIdx.x;
  const long m0 = (long)blockIdx.x * 64;
  if (tid < 64) {
    float mean = stats[tid] * CNTinv;
    float var = stats[64 + tid] * CNTinv - mean * mean;
    float sc = gamma[tid] * rsqrtf(var + EPSc);
    scs[tid] = sc;
    shs[tid] = beta[tid] - mean * sc;
  }
  for (int e = tid; e < 64 * COUT; e += 256) {
    int c = e >> 6, j = e & 63;
    Wt[j][c] = W[e];
  }
  __syncthreads();
  {
    const int p = tid >> 2, qd = tid & 3;
    const unsigned short* row = (const unsigned short*)xin + (m0 + p) * 64 + qd * 16;
    u16x8 a = *(const u16x8*)row;
    u16x8 bv = *(const u16x8*)(row + 8);
    const int j0 = qd * 16;
#pragma unroll
    for (int u = 0; u < 8; ++u) {
      float f = bf2f(a[u]);
      feats[j0 + u][p] = fmaxf(fmaf(scs[j0 + u], f, shs[j0 + u]), 0.f);
    }
#pragma unroll
    for (int u = 0; u < 8; ++u) {
      float f = bf2f(bv[u]);
      feats[j0 + 8 + u][p] = fmaxf(fmaf(scs[j0 + 8 + u], f, shs[j0 + 8 + u]), 0.f);
    }
  }
  __syncthreads();
  const int c0 = (tid & 15) * CB, p0 = (tid >> 4) * 4;
  float acc[4][CB];
#pragma unroll
  for (int cc = 0; cc < CB; ++cc) {
    float bb = bias[c0 + cc];
#pragma unroll
    for (int pp = 0; pp < 4; ++pp) acc[pp][cc] = bb;
  }
#pragma unroll 4
  for (int j = 0; j < 64; ++j) {
    const float4 f = *(const float4*)&feats[j][p0];
    const float fa[4] = {f.x, f.y, f.z, f.w};
#pragma unroll
    for (int cb = 0; cb < CB; cb += 4) {
      const float4 wv = *(const float4*)&Wt[j][c0 + cb];
      const float wa[4] = {wv.x, wv.y, wv.z, wv.w};
#pragma unroll
      for (int pp = 0; pp < 4; ++pp)
#pragma unroll
        for (int cc = 0; cc < 4; ++cc)
          acc[pp][cb + cc] = fmaf(fa[pp], wa[cc], acc[pp][cb + cc]);
    }
  }
#pragma unroll
  for (int pp = 0; pp < 4; ++pp) {
    unsigned pk[CB / 2];
#pragma unroll
    for (int u = 0; u < CB / 2; ++u) pk[u] = pack_bf2(acc[pp][2 * u], acc[pp][2 * u + 1]);
    unsigned short* dst = (unsigned short*)xout + (m0 + p0 + pp) * COUT + c0;
    if constexpr (CB == 4) {
      *(uint2*)dst = make_uint2(pk[0], pk[1]);
    } else {
      *(uint4*)dst = make_uint4(pk[0], pk[1], pk[2], pk[3]);
    }
  }
}

// ---------------- per-channel sum & sumsq over M rows ----------------
template <int C>
__global__ __launch_bounds__(256) void stats_kernel(const __hip_bfloat16* __restrict__ x,
                                                    float* __restrict__ out) {
  constexpr int G = C / 4;
  const int tid = threadIdx.x;
  const int g = tid % G;
  float s[4] = {0.f, 0.f, 0.f, 0.f}, qq[4] = {0.f, 0.f, 0.f, 0.f};
  const int rstep = (int)gridDim.x * (256 / G);
  for (int r = blockIdx.x * (256 / G) + tid / G; r < Mtot; r += rstep) {
    ushort4 v = *(const ushort4*)((const unsigned short*)x + (size_t)r * C + g * 4);
    float f0 = bf2f(v.x), f1 = bf2f(v.y), f2 = bf2f(v.z), f3 = bf2f(v.w);
    s[0] += f0; qq[0] += f0 * f0;
    s[1] += f1; qq[1] += f1 * f1;
    s[2] += f2; qq[2] += f2 * f2;
    s[3] += f3; qq[3] += f3 * f3;
  }
#pragma unroll
  for (int off = 32; off >= G; off >>= 1) {
#pragma unroll
    for (int u = 0; u < 4; ++u) {
      s[u] += __shfl_xor(s[u], off, 64);
      qq[u] += __shfl_xor(qq[u], off, 64);
    }
  }
  __shared__ float sm[4][G][8];
  const int lane = tid & 63, w = tid >> 6;
  if (lane < G) {
#pragma unroll
    for (int u = 0; u < 4; ++u) {
      sm[w][lane][u] = s[u];
      sm[w][lane][4 + u] = qq[u];
    }
  }
  __syncthreads();
  if (tid < C) {
    float ts = 0.f, tq = 0.f;
#pragma unroll
    for (int w2 = 0; w2 < 4; ++w2) {
      ts += sm[w2][tid >> 2][tid & 3];
      tq += sm[w2][tid >> 2][4 + (tid & 3)];
    }
    atomicAdd(&out[tid], ts);
    atomicAdd(&out[C + tid], tq);
  }
}

// ---------------- BN3 + ReLU + max over K, write [B,128,S] ----------------
__global__ __launch_bounds__(256) void pool_kernel(const __hip_bfloat16* __restrict__ x3,
                                                   const float* __restrict__ stats,
                                                   const float* __restrict__ gamma,
                                                   const float* __restrict__ beta,
                                                   float* __restrict__ out) {
  __shared__ float sc[128], sh[128];
  __shared__ float res[128][33];
  const int tid = threadIdx.x;
  if (tid < 128) {
    float mean = stats[tid] * CNTinv;
    float var = stats[128 + tid] * CNTinv - mean * mean;
    float s = gamma[tid] * rsqrtf(var + EPSc);
    sc[tid] = s;
    sh[tid] = beta[tid] - mean * s;
  }
  __syncthreads();
  const int b = blockIdx.x >> 5;
  const int s0 = (blockIdx.x & 31) * 32;
  const int w = tid >> 6, lane = tid & 63;
  const int c0 = lane * 2;
  const float sc0 = sc[c0], sh0 = sh[c0], sc1 = sc[c0 + 1], sh1 = sh[c0 + 1];
  for (int si = 0; si < 8; ++si) {
    const int s = s0 + w * 8 + si;
    const unsigned* row =
        (const unsigned*)((const unsigned short*)x3 + (size_t)((b * Sc + s) * Kc) * 128) + lane;
    float m0 = -1e30f, m1 = -1e30f;
#pragma unroll 8
    for (int k = 0; k < Kc; ++k) {
      unsigned v = row[k * 64];
      float f0 = bf2f((unsigned short)(v & 0xFFFFu));
      float f1 = bf2f((unsigned short)(v >> 16));
      m0 = fmaxf(m0, fmaxf(fmaf(sc0, f0, sh0), 0.f));
      m1 = fmaxf(m1, fmaxf(fmaf(sc1, f1, sh1), 0.f));
    }
    res[c0][s - s0] = m0;
    res[c0 + 1][s - s0] = m1;
  }
  __syncthreads();
  const int c = tid >> 1, h = tid & 1;
  float* ob = out + (size_t)b * 128 * Sc + (size_t)c * Sc + s0 + h * 16;
#pragma unroll
  for (int u = 0; u < 16; ++u) ob[u] = res[c][h * 16 + u];
}

extern "C" void kernel_launch(void* const* d_in, const int* in_sizes, int n_in,
                              void* d_out, int out_size, void* d_ws, size_t ws_size,
                              hipStream_t stream) {
  const float* xyz = (const float*)d_in[0];
  const float* points = (const float*)d_in[1];
  const float* W1 = (const float*)d_in[2];
  const float* b1 = (const float*)d_in[3];
  const float* g1 = (const float*)d_in[4];
  const float* bt1 = (const float*)d_in[5];
  const float* W2 = (const float*)d_in[6];
  const float* b2 = (const float*)d_in[7];
  const float* g2 = (const float*)d_in[8];
  const float* bt2 = (const float*)d_in[9];
  const float* W3 = (const float*)d_in[10];
  const float* b3 = (const float*)d_in[11];
  const float* g3 = (const float*)d_in[12];
  const float* bt3 = (const float*)d_in[13];
  float* out = (float*)d_out;

  char* ws = (char*)d_ws;
  // layout: fidx[64KB] | idx[2MB] | stats[2KB] | x2[64MB] | x1/x3 alias [128MB]
  int* fidx = (int*)(ws + 0);
  int* idx = (int*)(ws + 65536);
  float* stats = (float*)(ws + 2162688);
  __hip_bfloat16* x2 = (__hip_bfloat16*)(ws + 2164736);
  __hip_bfloat16* x1 = (__hip_bfloat16*)(ws + 2164736 + 67108864);
  __hip_bfloat16* x3 = x1;  // x1 is dead before conv3 writes

  hipMemsetAsync(stats, 0, 512 * sizeof(float), stream);
  fps_kernel<<<Bc, 512, 0, stream>>>(xyz, fidx);
  knn_kernel<<<Bc * Sc / 4, 256, 0, stream>>>(xyz, fidx, out, idx);
  conv1_kernel<<<Mtot / 64, 256, 0, stream>>>(xyz, points, out, idx, W1, b1, x1);
  stats_kernel<64><<<512, 256, 0, stream>>>(x1, stats);
  convN_kernel<64><<<Mtot / 64, 256, 0, stream>>>(x1, stats, g1, bt1, W2, b2, x2);
  stats_kernel<64><<<512, 256, 0, stream>>>(x2, stats + 128);
  convN_kernel<128><<<Mtot / 64, 256, 0, stream>>>(x2, stats + 128, g2, bt2, W3, b3, x3);
  stats_kernel<128><<<512, 256, 0, stream>>>(x3, stats + 256);
  pool_kernel<<<Bc * (Sc / 32), 256, 0, stream>>>(x3, stats + 256, g3, bt3, out + Bc * Sc * 3);
}

// Round 2
// 2378.490 us; speedup vs baseline: 1.2609x; 1.2609x over previous
//
#include <hip/hip_runtime.h>
#include <hip/hip_bf16.h>

typedef __attribute__((ext_vector_type(8))) unsigned short u16x8;

#define DEVI __device__ __forceinline__

constexpr int Bc = 16;
constexpr int Nc = 4096;
constexpr int Sc = 1024;   // NPOINT
constexpr int Kc = 32;
constexpr int Dc = 64;
constexpr int C1 = 67;
constexpr int Mtot = Bc * Sc * Kc;  // 524288
constexpr float EPSc = 1e-5f;
constexpr float CNTinv = 1.0f / (float)Mtot;

// no-FMA squared distance, matches numpy (x*x + y*y) + z*z
DEVI float sqdist3(float dx, float dy, float dz) {
  return __fadd_rn(__fadd_rn(__fmul_rn(dx, dx), __fmul_rn(dy, dy)), __fmul_rn(dz, dz));
}
DEVI unsigned long long umax64(unsigned long long a, unsigned long long b) { return a > b ? a : b; }
DEVI unsigned long long umin64(unsigned long long a, unsigned long long b) { return a < b ? a : b; }
DEVI float bf2f(unsigned short u) { return __uint_as_float(((unsigned)u) << 16); }
DEVI unsigned pack_bf2(float a, float b) {
  __hip_bfloat16 ha = __float2bfloat16(a), hb = __float2bfloat16(b);
  unsigned short ua, ub;
  __builtin_memcpy(&ua, &ha, 2);
  __builtin_memcpy(&ub, &hb, 2);
  return (unsigned)ua | ((unsigned)ub << 16);
}

// ---------------- FPS: one block per batch, 1 barrier/step, swizzle reduce ----------------
__global__ __launch_bounds__(512) void fps_kernel(const float* __restrict__ xyz,
                                                  int* __restrict__ fidx) {
  __shared__ float lsx[Nc], lsy[Nc], lsz[Nc];           // 48 KiB coord table (read-only in loop)
  __shared__ __align__(16) unsigned long long wkey[2][8];
  __shared__ int sidx[Sc];
  const int b = blockIdx.x;
  const float* xb = xyz + (size_t)b * Nc * 3;
  const int tid = threadIdx.x;
  const int lane = tid & 63, w = tid >> 6;

  float px[8], py[8], pz[8], dist[8];
  int pc[8];
#pragma unroll
  for (int i = 0; i < 8; ++i) {
    int p = tid + i * 512;
    px[i] = xb[p * 3 + 0];
    py[i] = xb[p * 3 + 1];
    pz[i] = xb[p * 3 + 2];
    dist[i] = 1e10f;
    pc[i] = p;
  }
  for (int e = tid; e < Nc; e += 512) {
    lsx[e] = xb[e * 3 + 0];
    lsy[e] = xb[e * 3 + 1];
    lsz[e] = xb[e * 3 + 2];
  }
  if (tid == 0) sidx[0] = 0;
  __syncthreads();

  int widx = 0;
  for (int t = 1; t < Sc; ++t) {
    const float cx = lsx[widx], cy = lsy[widx], cz = lsz[widx];
    float bd = -1.0f;
    int bp = 0;
#pragma unroll
    for (int i = 0; i < 8; ++i) {
      float d = sqdist3(px[i] - cx, py[i] - cy, pz[i] - cz);
      float nd = fminf(dist[i], d);
      dist[i] = nd;
      if (nd > bd) { bd = nd; bp = pc[i]; }  // strict > keeps smallest p within lane
    }
    // pack key: larger dist wins; tie -> larger complement = smaller index
    unsigned lo = 0xFFFFFFFFu - (unsigned)bp;
    unsigned hi = __float_as_uint(bd);
    // wave64 max-reduce: ds_swizzle xor 1,2,4,8,16 (within 32-lane halves) + shfl across halves
#define SWZ_STAGE(OFF)                                                              \
    {                                                                               \
      unsigned olo = (unsigned)__builtin_amdgcn_ds_swizzle((int)lo, OFF);           \
      unsigned ohi = (unsigned)__builtin_amdgcn_ds_swizzle((int)hi, OFF);           \
      unsigned long long cur = ((unsigned long long)hi << 32) | lo;                 \
      unsigned long long oth = ((unsigned long long)ohi << 32) | olo;               \
      if (oth > cur) { hi = ohi; lo = olo; }                                        \
    }
    SWZ_STAGE(0x041F)
    SWZ_STAGE(0x081F)
    SWZ_STAGE(0x101F)
    SWZ_STAGE(0x201F)
    SWZ_STAGE(0x401F)
#undef SWZ_STAGE
    {
      unsigned olo = (unsigned)__shfl_xor((int)lo, 32, 64);
      unsigned ohi = (unsigned)__shfl_xor((int)hi, 32, 64);
      unsigned long long cur = ((unsigned long long)hi << 32) | lo;
      unsigned long long oth = ((unsigned long long)ohi << 32) | olo;
      if (oth > cur) { hi = ohi; lo = olo; }
    }
    if (lane == 0) wkey[t & 1][w] = ((unsigned long long)hi << 32) | lo;
    __syncthreads();
    const ulonglong2* wp = (const ulonglong2*)wkey[t & 1];
    ulonglong2 a0 = wp[0], a1 = wp[1], a2 = wp[2], a3 = wp[3];
    unsigned long long m = umax64(umax64(umax64(a0.x, a0.y), umax64(a1.x, a1.y)),
                                  umax64(umax64(a2.x, a2.y), umax64(a3.x, a3.y)));
    widx = (int)(0xFFFFFFFFu - (unsigned)(m & 0xFFFFFFFFu));
    if (tid == 0) sidx[t] = widx;
  }
  __syncthreads();
  for (int e = tid; e < Sc; e += 512) fidx[b * Sc + e] = sidx[e];
}

// ---------------- kNN: one wave per query, LDS distance array, 32 argmin rounds ----------------
__global__ __launch_bounds__(256) void knn_kernel(const float* __restrict__ xyz,
                                                  const int* __restrict__ fidx,
                                                  float* __restrict__ new_xyz,
                                                  int* __restrict__ idx) {
  __shared__ float dls[4][Nc];  // 64 KiB
  const int w = threadIdx.x >> 6;
  const int lane = threadIdx.x & 63;
  const int q = blockIdx.x * 4 + w;
  const int b = q >> 10;
  const int s = q & (Sc - 1);
  const float* xb = xyz + (size_t)b * Nc * 3;
  const int ci = fidx[b * Sc + s];
  const float cx = xb[ci * 3 + 0], cy = xb[ci * 3 + 1], cz = xb[ci * 3 + 2];
  if (lane == 0) {
    new_xyz[(b * Sc + s) * 3 + 0] = cx;
    new_xyz[(b * Sc + s) * 3 + 1] = cy;
    new_xyz[(b * Sc + s) * 3 + 2] = cz;
  }
  float* dl = dls[w];
  for (int j = lane; j < Nc; j += 64) {
    dl[j] = sqdist3(xb[j * 3 + 0] - cx, xb[j * 3 + 1] - cy, xb[j * 3 + 2] - cz);
  }
  int* outp = idx + ((size_t)b * Sc + s) * Kc;
  for (int r = 0; r < Kc; ++r) {
    unsigned long long best = ~0ull;
    for (int j = lane; j < Nc; j += 64) {
      unsigned long long key = ((unsigned long long)__float_as_uint(dl[j]) << 32) | (unsigned)j;
      best = umin64(best, key);
    }
#pragma unroll
    for (int off = 32; off > 0; off >>= 1) {
      unsigned long long o = __shfl_xor(best, off, 64);
      best = umin64(best, o);
    }
    const unsigned wj = (unsigned)(best & 0xFFFFFFFFu);
    if (lane == (int)(wj & 63u)) dl[wj] = __uint_as_float(0x7F800000u);  // +inf
    if (lane == 0) outp[r] = (int)wj;
  }
}

// ---------------- conv1: gather (3 xyz-diff + 64 point feats) -> 64 channels ----------------
__global__ __launch_bounds__(256) void conv1_kernel(
    const float* __restrict__ xyz, const float* __restrict__ points,
    const float* __restrict__ new_xyz, const int* __restrict__ idx,
    const float* __restrict__ W1, const float* __restrict__ b1,
    __hip_bfloat16* __restrict__ x1) {
  __shared__ float feats[C1][68];
  __shared__ float Wt[C1][64];
  const int tid = threadIdx.x;
  const int m0 = blockIdx.x * 64;
  for (int e = tid; e < 64 * C1; e += 256) {
    int c = e / C1, j = e % C1;
    Wt[j][c] = W1[e];
  }
  {
    const int p = tid >> 2, qd = tid & 3;
    const int m = m0 + p;
    const int b = m >> 15;             // /(S*K)
    const int s = (m >> 5) & (Sc - 1); // (m/K)%S
    const int i = idx[m];
    const float* pr = points + ((size_t)b * Nc + i) * Dc + qd * 16;
    float4 v0 = *(const float4*)(pr + 0);
    float4 v1 = *(const float4*)(pr + 4);
    float4 v2 = *(const float4*)(pr + 8);
    float4 v3 = *(const float4*)(pr + 12);
    float vv[16] = {v0.x, v0.y, v0.z, v0.w, v1.x, v1.y, v1.z, v1.w,
                    v2.x, v2.y, v2.z, v2.w, v3.x, v3.y, v3.z, v3.w};
    const int j0 = 3 + qd * 16;
#pragma unroll
    for (int u = 0; u < 16; ++u) feats[j0 + u][p] = vv[u];
    if (qd == 0) {
      const float* xp = xyz + ((size_t)b * Nc + i) * 3;
      const float* cp = new_xyz + ((size_t)b * Sc + s) * 3;
      feats[0][p] = xp[0] - cp[0];
      feats[1][p] = xp[1] - cp[1];
      feats[2][p] = xp[2] - cp[2];
    }
  }
  __syncthreads();
  const int c0 = (tid & 15) * 4, p0 = (tid >> 4) * 4;
  float acc[4][4];
#pragma unroll
  for (int cc = 0; cc < 4; ++cc) {
    float bb = b1[c0 + cc];
#pragma unroll
    for (int pp = 0; pp < 4; ++pp) acc[pp][cc] = bb;
  }
#pragma unroll 4
  for (int j = 0; j < C1; ++j) {
    const float4 f = *(const float4*)&feats[j][p0];
    const float4 wv = *(const float4*)&Wt[j][c0];
    const float fa[4] = {f.x, f.y, f.z, f.w};
    const float wa[4] = {wv.x, wv.y, wv.z, wv.w};
#pragma unroll
    for (int pp = 0; pp < 4; ++pp)
#pragma unroll
      for (int cc = 0; cc < 4; ++cc) acc[pp][cc] = fmaf(fa[pp], wa[cc], acc[pp][cc]);
  }
#pragma unroll
  for (int pp = 0; pp < 4; ++pp) {
    unsigned r0 = pack_bf2(acc[pp][0], acc[pp][1]);
    unsigned r1 = pack_bf2(acc[pp][2], acc[pp][3]);
    unsigned short* dst = (unsigned short*)x1 + (size_t)(m0 + p0 + pp) * 64 + c0;
    *(uint2*)dst = make_uint2(r0, r1);
  }
}

// ---------------- convN: BN(prev)+ReLU on input, then 64 -> COUT conv ----------------
template <int COUT>
__global__ __launch_bounds__(256) void convN_kernel(
    const __hip_bfloat16* __restrict__ xin, const float* __restrict__ stats,
    const float* __restrict__ gamma, const float* __restrict__ beta,
    const float* __restrict__ W, const float* __restrict__ bias,
    __hip_bfloat16* __restrict__ xout) {
  constexpr int CB = COUT / 16;
  __shared__ float feats[64][68];
  __shared__ float Wt[64][COUT];
  __shared__ float scs[64], shs[64];
  const int tid = threadIdx.x;
  const long m0 = (long)blockIdx.x * 64;
  if (tid < 64) {
    float mean = stats[tid] * CNTinv;
    float var = stats[64 + tid] * CNTinv - mean * mean;
    float sc = gamma[tid] * rsqrtf(var + EPSc);
    scs[tid] = sc;
    shs[tid] = beta[tid] - mean * sc;
  }
  for (int e = tid; e < 64 * COUT; e += 256) {
    int c = e >> 6, j = e & 63;
    Wt[j][c] = W[e];
  }
  __syncthreads();
  {
    const int p = tid >> 2, qd = tid & 3;
    const unsigned short* row = (const unsigned short*)xin + (m0 + p) * 64 + qd * 16;
    u16x8 a = *(const u16x8*)row;
    u16x8 bv = *(const u16x8*)(row + 8);
    const int j0 = qd * 16;
#pragma unroll
    for (int u = 0; u < 8; ++u) {
      float f = bf2f(a[u]);
      feats[j0 + u][p] = fmaxf(fmaf(scs[j0 + u], f, shs[j0 + u]), 0.f);
    }
#pragma unroll
    for (int u = 0; u < 8; ++u) {
      float f = bf2f(bv[u]);
      feats[j0 + 8 + u][p] = fmaxf(fmaf(scs[j0 + 8 + u], f, shs[j0 + 8 + u]), 0.f);
    }
  }
  __syncthreads();
  const int c0 = (tid & 15) * CB, p0 = (tid >> 4) * 4;
  float acc[4][CB];
#pragma unroll
  for (int cc = 0; cc < CB; ++cc) {
    float bb = bias[c0 + cc];
#pragma unroll
    for (int pp = 0; pp < 4; ++pp) acc[pp][cc] = bb;
  }
#pragma unroll 4
  for (int j = 0; j < 64; ++j) {
    const float4 f = *(const float4*)&feats[j][p0];
    const float fa[4] = {f.x, f.y, f.z, f.w};
#pragma unroll
    for (int cb = 0; cb < CB; cb += 4) {
      const float4 wv = *(const float4*)&Wt[j][c0 + cb];
      const float wa[4] = {wv.x, wv.y, wv.z, wv.w};
#pragma unroll
      for (int pp = 0; pp < 4; ++pp)
#pragma unroll
        for (int cc = 0; cc < 4; ++cc)
          acc[pp][cb + cc] = fmaf(fa[pp], wa[cc], acc[pp][cb + cc]);
    }
  }
#pragma unroll
  for (int pp = 0; pp < 4; ++pp) {
    unsigned pk[CB / 2];
#pragma unroll
    for (int u = 0; u < CB / 2; ++u) pk[u] = pack_bf2(acc[pp][2 * u], acc[pp][2 * u + 1]);
    unsigned short* dst = (unsigned short*)xout + (m0 + p0 + pp) * COUT + c0;
    if constexpr (CB == 4) {
      *(uint2*)dst = make_uint2(pk[0], pk[1]);
    } else {
      *(uint4*)dst = make_uint4(pk[0], pk[1], pk[2], pk[3]);
    }
  }
}

// ---------------- per-channel sum & sumsq over M rows ----------------
template <int C>
__global__ __launch_bounds__(256) void stats_kernel(const __hip_bfloat16* __restrict__ x,
                                                    float* __restrict__ out) {
  constexpr int G = C / 4;
  const int tid = threadIdx.x;
  const int g = tid % G;
  float s[4] = {0.f, 0.f, 0.f, 0.f}, qq[4] = {0.f, 0.f, 0.f, 0.f};
  const int rstep = (int)gridDim.x * (256 / G);
  for (int r = blockIdx.x * (256 / G) + tid / G; r < Mtot; r += rstep) {
    ushort4 v = *(const ushort4*)((const unsigned short*)x + (size_t)r * C + g * 4);
    float f0 = bf2f(v.x), f1 = bf2f(v.y), f2 = bf2f(v.z), f3 = bf2f(v.w);
    s[0] += f0; qq[0] += f0 * f0;
    s[1] += f1; qq[1] += f1 * f1;
    s[2] += f2; qq[2] += f2 * f2;
    s[3] += f3; qq[3] += f3 * f3;
  }
#pragma unroll
  for (int off = 32; off >= G; off >>= 1) {
#pragma unroll
    for (int u = 0; u < 4; ++u) {
      s[u] += __shfl_xor(s[u], off, 64);
      qq[u] += __shfl_xor(qq[u], off, 64);
    }
  }
  __shared__ float sm[4][G][8];
  const int lane = tid & 63, w = tid >> 6;
  if (lane < G) {
#pragma unroll
    for (int u = 0; u < 4; ++u) {
      sm[w][lane][u] = s[u];
      sm[w][lane][4 + u] = qq[u];
    }
  }
  __syncthreads();
  if (tid < C) {
    float ts = 0.f, tq = 0.f;
#pragma unroll
    for (int w2 = 0; w2 < 4; ++w2) {
      ts += sm[w2][tid >> 2][tid & 3];
      tq += sm[w2][tid >> 2][4 + (tid & 3)];
    }
    atomicAdd(&out[tid], ts);
    atomicAdd(&out[C + tid], tq);
  }
}

// ---------------- BN3 + ReLU + max over K, write [B,128,S] ----------------
__global__ __launch_bounds__(256) void pool_kernel(const __hip_bfloat16* __restrict__ x3,
                                                   const float* __restrict__ stats,
                                                   const float* __restrict__ gamma,
                                                   const float* __restrict__ beta,
                                                   float* __restrict__ out) {
  __shared__ float sc[128], sh[128];
  __shared__ float res[128][33];
  const int tid = threadIdx.x;
  if (tid < 128) {
    float mean = stats[tid] * CNTinv;
    float var = stats[128 + tid] * CNTinv - mean * mean;
    float s = gamma[tid] * rsqrtf(var + EPSc);
    sc[tid] = s;
    sh[tid] = beta[tid] - mean * s;
  }
  __syncthreads();
  const int b = blockIdx.x >> 5;
  const int s0 = (blockIdx.x & 31) * 32;
  const int w = tid >> 6, lane = tid & 63;
  const int c0 = lane * 2;
  const float sc0 = sc[c0], sh0 = sh[c0], sc1 = sc[c0 + 1], sh1 = sh[c0 + 1];
  for (int si = 0; si < 8; ++si) {
    const int s = s0 + w * 8 + si;
    const unsigned* row =
        (const unsigned*)((const unsigned short*)x3 + (size_t)((b * Sc + s) * Kc) * 128) + lane;
    float m0 = -1e30f, m1 = -1e30f;
#pragma unroll 8
    for (int k = 0; k < Kc; ++k) {
      unsigned v = row[k * 64];
      float f0 = bf2f((unsigned short)(v & 0xFFFFu));
      float f1 = bf2f((unsigned short)(v >> 16));
      m0 = fmaxf(m0, fmaxf(fmaf(sc0, f0, sh0), 0.f));
      m1 = fmaxf(m1, fmaxf(fmaf(sc1, f1, sh1), 0.f));
    }
    res[c0][s - s0] = m0;
    res[c0 + 1][s - s0] = m1;
  }
  __syncthreads();
  const int c = tid >> 1, h = tid & 1;
  float* ob = out + (size_t)b * 128 * Sc + (size_t)c * Sc + s0 + h * 16;
#pragma unroll
  for (int u = 0; u < 16; ++u) ob[u] = res[c][h * 16 + u];
}

extern "C" void kernel_launch(void* const* d_in, const int* in_sizes, int n_in,
                              void* d_out, int out_size, void* d_ws, size_t ws_size,
                              hipStream_t stream) {
  const float* xyz = (const float*)d_in[0];
  const float* points = (const float*)d_in[1];
  const float* W1 = (const float*)d_in[2];
  const float* b1 = (const float*)d_in[3];
  const float* g1 = (const float*)d_in[4];
  const float* bt1 = (const float*)d_in[5];
  const float* W2 = (const float*)d_in[6];
  const float* b2 = (const float*)d_in[7];
  const float* g2 = (const float*)d_in[8];
  const float* bt2 = (const float*)d_in[9];
  const float* W3 = (const float*)d_in[10];
  const float* b3 = (const float*)d_in[11];
  const float* g3 = (const float*)d_in[12];
  const float* bt3 = (const float*)d_in[13];
  float* out = (float*)d_out;

  char* ws = (char*)d_ws;
  // layout: fidx[64KB] | idx[2MB] | stats[2KB] | x2[64MB] | x1/x3 alias [128MB]
  int* fidx = (int*)(ws + 0);
  int* idx = (int*)(ws + 65536);
  float* stats = (float*)(ws + 2162688);
  __hip_bfloat16* x2 = (__hip_bfloat16*)(ws + 2164736);
  __hip_bfloat16* x1 = (__hip_bfloat16*)(ws + 2164736 + 67108864);
  __hip_bfloat16* x3 = x1;  // x1 is dead before conv3 writes

  hipMemsetAsync(stats, 0, 512 * sizeof(float), stream);
  fps_kernel<<<Bc, 512, 0, stream>>>(xyz, fidx);
  knn_kernel<<<Bc * Sc / 4, 256, 0, stream>>>(xyz, fidx, out, idx);
  conv1_kernel<<<Mtot / 64, 256, 0, stream>>>(xyz, points, out, idx, W1, b1, x1);
  stats_kernel<64><<<512, 256, 0, stream>>>(x1, stats);
  convN_kernel<64><<<Mtot / 64, 256, 0, stream>>>(x1, stats, g1, bt1, W2, b2, x2);
  stats_kernel<64><<<512, 256, 0, stream>>>(x2, stats + 128);
  convN_kernel<128><<<Mtot / 64, 256, 0, stream>>>(x2, stats + 128, g2, bt2, W3, b3, x3);
  stats_kernel<128><<<512, 256, 0, stream>>>(x3, stats + 256);
  pool_kernel<<<Bc * (Sc / 32), 256, 0, stream>>>(x3, stats + 256, g3, bt3, out + Bc * Sc * 3);
}

// Round 3
// 1528.649 us; speedup vs baseline: 1.9619x; 1.5559x over previous
//
#include <hip/hip_runtime.h>
#include <hip/hip_bf16.h>

typedef __attribute__((ext_vector_type(8))) unsigned short u16x8;

#define DEVI __device__ __forceinline__

constexpr int Bc = 16;
constexpr int Nc = 4096;
constexpr int Sc = 1024;   // NPOINT
constexpr int Kc = 32;
constexpr int Dc = 64;
constexpr int C1 = 67;
constexpr int Mtot = Bc * Sc * Kc;  // 524288
constexpr float EPSc = 1e-5f;
constexpr float CNTinv = 1.0f / (float)Mtot;

// no-FMA squared distance, matches numpy (x*x + y*y) + z*z
DEVI float sqdist3(float dx, float dy, float dz) {
  return __fadd_rn(__fadd_rn(__fmul_rn(dx, dx), __fmul_rn(dy, dy)), __fmul_rn(dz, dz));
}
DEVI unsigned long long umax64(unsigned long long a, unsigned long long b) { return a > b ? a : b; }
DEVI float bf2f(unsigned short u) { return __uint_as_float(((unsigned)u) << 16); }
DEVI unsigned pack_bf2(float a, float b) {
  __hip_bfloat16 ha = __float2bfloat16(a), hb = __float2bfloat16(b);
  unsigned short ua, ub;
  __builtin_memcpy(&ua, &ha, 2);
  __builtin_memcpy(&ub, &hb, 2);
  return (unsigned)ua | ((unsigned)ub << 16);
}

// ---- wave64 DPP reductions: result broadcast via readlane(63) ----
// stages: quad_perm xor1, xor2, row_half_mirror (xor4), row_mirror (xor8),
// bcast15 (rows 1,3), bcast31 (rows 2,3) -> lane 63 holds full reduction.
#define DPP_STAGE(v, OP, CTRL, MASK)                                                       \
  {                                                                                        \
    int _t = __builtin_amdgcn_update_dpp(__float_as_int(v), __float_as_int(v), CTRL, MASK, \
                                         0xF, false);                                      \
    v = OP(v, __int_as_float(_t));                                                         \
  }
DEVI float wave_fmax63(float v) {
  DPP_STAGE(v, fmaxf, 0xB1, 0xF)
  DPP_STAGE(v, fmaxf, 0x4E, 0xF)
  DPP_STAGE(v, fmaxf, 0x141, 0xF)
  DPP_STAGE(v, fmaxf, 0x140, 0xF)
  DPP_STAGE(v, fmaxf, 0x142, 0xA)
  DPP_STAGE(v, fmaxf, 0x143, 0xC)
  return __int_as_float(__builtin_amdgcn_readlane(__float_as_int(v), 63));
}
DEVI float wave_fmin63(float v) {
  DPP_STAGE(v, fminf, 0xB1, 0xF)
  DPP_STAGE(v, fminf, 0x4E, 0xF)
  DPP_STAGE(v, fminf, 0x141, 0xF)
  DPP_STAGE(v, fminf, 0x140, 0xF)
  DPP_STAGE(v, fminf, 0x142, 0xA)
  DPP_STAGE(v, fminf, 0x143, 0xC)
  return __int_as_float(__builtin_amdgcn_readlane(__float_as_int(v), 63));
}
#define DPP_STAGE_U(v, CTRL, MASK)                                                      \
  {                                                                                     \
    unsigned _t = (unsigned)__builtin_amdgcn_update_dpp((int)(v), (int)(v), CTRL, MASK, \
                                                        0xF, false);                    \
    v = (_t < v) ? _t : v;                                                              \
  }
DEVI unsigned wave_umin63(unsigned v) {
  DPP_STAGE_U(v, 0xB1, 0xF)
  DPP_STAGE_U(v, 0x4E, 0xF)
  DPP_STAGE_U(v, 0x141, 0xF)
  DPP_STAGE_U(v, 0x140, 0xF)
  DPP_STAGE_U(v, 0x142, 0xA)
  DPP_STAGE_U(v, 0x143, 0xC)
  return (unsigned)__builtin_amdgcn_readlane((int)v, 63);
}

// ---------------- FPS: one block per batch, 1 barrier/step, DPP reduce ----------------
__global__ __launch_bounds__(512) void fps_kernel(const float* __restrict__ xyz,
                                                  int* __restrict__ fidx) {
  __shared__ float lsx[Nc], lsy[Nc], lsz[Nc];  // 48 KiB coord table (read-only in loop)
  __shared__ __align__(16) unsigned long long wkey[2][8];
  __shared__ int sidx[Sc];
  const int b = blockIdx.x;
  const float* xb = xyz + (size_t)b * Nc * 3;
  const int tid = threadIdx.x;
  const int lane = tid & 63, w = tid >> 6;

  float px[8], py[8], pz[8], dist[8];
#pragma unroll
  for (int i = 0; i < 8; ++i) {
    int p = tid + i * 512;
    px[i] = xb[p * 3 + 0];
    py[i] = xb[p * 3 + 1];
    pz[i] = xb[p * 3 + 2];
    dist[i] = 1e10f;
  }
  for (int e = tid; e < Nc; e += 512) {
    lsx[e] = xb[e * 3 + 0];
    lsy[e] = xb[e * 3 + 1];
    lsz[e] = xb[e * 3 + 2];
  }
  if (tid == 0) sidx[0] = 0;
  __syncthreads();

  int widx = 0;
  for (int t = 1; t < Sc; ++t) {
    const float cx = lsx[widx], cy = lsy[widx], cz = lsz[widx];
    float bd = -1.0f;
    unsigned bp = 0;
#pragma unroll
    for (int i = 0; i < 8; ++i) {
      float d = sqdist3(px[i] - cx, py[i] - cy, pz[i] - cz);
      float nd = fminf(dist[i], d);
      dist[i] = nd;
      if (nd > bd) { bd = nd; bp = (unsigned)(tid + i * 512); }  // strict > keeps smallest p
    }
    const float maxd = wave_fmax63(bd);
    unsigned cp = (bd == maxd) ? bp : 0xFFFFFFFFu;
    const unsigned minp = wave_umin63(cp);  // smallest index among ties -> argmax semantics
    if (lane == 0)
      wkey[t & 1][w] = ((unsigned long long)__float_as_uint(maxd) << 32) |
                       (unsigned long long)(0xFFFFFFFFu - minp);
    __syncthreads();
    const ulonglong2* wp = (const ulonglong2*)wkey[t & 1];
    ulonglong2 a0 = wp[0], a1 = wp[1], a2 = wp[2], a3 = wp[3];
    unsigned long long m = umax64(umax64(umax64(a0.x, a0.y), umax64(a1.x, a1.y)),
                                  umax64(umax64(a2.x, a2.y), umax64(a3.x, a3.y)));
    widx = (int)(0xFFFFFFFFu - (unsigned)(m & 0xFFFFFFFFu));
    if (tid == 0) sidx[t] = widx;
  }
  __syncthreads();
  for (int e = tid; e < Sc; e += 512) fidx[b * Sc + e] = sidx[e];
}

// ---------------- kNN: one wave/query, top-2 cache + taken mask, DPP argmin ----------------
__global__ __launch_bounds__(256) void knn_kernel(const float* __restrict__ xyz,
                                                  const int* __restrict__ fidx,
                                                  float* __restrict__ new_xyz,
                                                  int* __restrict__ idx) {
  const int w = threadIdx.x >> 6;
  const int lane = threadIdx.x & 63;
  const int q = blockIdx.x * 4 + w;
  const int b = q >> 10;
  const int s = q & (Sc - 1);
  const float* xb = xyz + (size_t)b * Nc * 3;
  const int ci = fidx[b * Sc + s];
  const float cx = xb[ci * 3 + 0], cy = xb[ci * 3 + 1], cz = xb[ci * 3 + 2];
  if (lane == 0) {
    new_xyz[(b * Sc + s) * 3 + 0] = cx;
    new_xyz[(b * Sc + s) * 3 + 1] = cy;
    new_xyz[(b * Sc + s) * 3 + 2] = cz;
  }
  const float INF = __int_as_float(0x7F800000);
  // lane owns points p = lane + 64*i, i in [0,64)
  const float* pp = xb + lane * 3;
  float d0 = INF, d1 = INF;
  int i0 = 0, i1 = 0;
#pragma unroll 4
  for (int i = 0; i < 64; ++i) {
    const float x = pp[i * 192 + 0], y = pp[i * 192 + 1], z = pp[i * 192 + 2];
    const float d = sqdist3(x - cx, y - cy, z - cz);
    const bool c0 = d < d0, c1 = d < d1;  // strict <: stable (earlier i kept on ties)
    d1 = c0 ? d0 : (c1 ? d : d1);
    i1 = c0 ? i0 : (c1 ? i : i1);
    d0 = c0 ? d : d0;
    i0 = c0 ? i : i0;
  }
  unsigned long long taken = 0ull;
  int* outp = idx + ((size_t)b * Sc + s) * Kc;
#pragma unroll 1
  for (int r = 0; r < Kc; ++r) {
    const float mind = wave_fmin63(d0);
    const unsigned myp = (unsigned)(lane + (i0 << 6));
    unsigned c = (d0 == mind) ? myp : 0xFFFFFFFFu;
    const unsigned W = wave_umin63(c);  // exact (dist, idx) lexicographic argmin
    if (lane == 0) outp[r] = (int)W;
    if (myp == W) {  // single winner lane
      taken |= (1ull << i0);
      d0 = d1;
      i0 = i1;
      d1 = INF;
      if (__float_as_uint(d0) == 0x7F800000u) {  // cache exhausted -> rebuild top-2
        float e0 = INF, e1 = INF;
        int j0 = 0, j1 = 0;
#pragma unroll 4
        for (int i = 0; i < 64; ++i) {
          const float x = pp[i * 192 + 0], y = pp[i * 192 + 1], z = pp[i * 192 + 2];
          float d = sqdist3(x - cx, y - cy, z - cz);
          d = ((taken >> i) & 1ull) ? INF : d;
          const bool c0b = d < e0, c1b = d < e1;
          e1 = c0b ? e0 : (c1b ? d : e1);
          j1 = c0b ? j0 : (c1b ? i : j1);
          e0 = c0b ? d : e0;
          j0 = c0b ? i : j0;
        }
        d0 = e0; i0 = j0; d1 = e1; i1 = j1;
      }
    }
  }
}

// ---------------- conv1: gather (3 xyz-diff + 64 point feats) -> 64 channels ----------------
__global__ __launch_bounds__(256) void conv1_kernel(
    const float* __restrict__ xyz, const float* __restrict__ points,
    const float* __restrict__ new_xyz, const int* __restrict__ idx,
    const float* __restrict__ W1, const float* __restrict__ b1,
    __hip_bfloat16* __restrict__ x1) {
  __shared__ float feats[C1][68];
  __shared__ float Wt[C1][64];
  const int tid = threadIdx.x;
  const int m0 = blockIdx.x * 64;
  for (int e = tid; e < 64 * C1; e += 256) {
    int c = e / C1, j = e % C1;
    Wt[j][c] = W1[e];
  }
  {
    const int p = tid >> 2, qd = tid & 3;
    const int m = m0 + p;
    const int b = m >> 15;             // /(S*K)
    const int s = (m >> 5) & (Sc - 1); // (m/K)%S
    const int i = idx[m];
    const float* pr = points + ((size_t)b * Nc + i) * Dc + qd * 16;
    float4 v0 = *(const float4*)(pr + 0);
    float4 v1 = *(const float4*)(pr + 4);
    float4 v2 = *(const float4*)(pr + 8);
    float4 v3 = *(const float4*)(pr + 12);
    float vv[16] = {v0.x, v0.y, v0.z, v0.w, v1.x, v1.y, v1.z, v1.w,
                    v2.x, v2.y, v2.z, v2.w, v3.x, v3.y, v3.z, v3.w};
    const int j0 = 3 + qd * 16;
#pragma unroll
    for (int u = 0; u < 16; ++u) feats[j0 + u][p] = vv[u];
    if (qd == 0) {
      const float* xp = xyz + ((size_t)b * Nc + i) * 3;
      const float* cp = new_xyz + ((size_t)b * Sc + s) * 3;
      feats[0][p] = xp[0] - cp[0];
      feats[1][p] = xp[1] - cp[1];
      feats[2][p] = xp[2] - cp[2];
    }
  }
  __syncthreads();
  const int c0 = (tid & 15) * 4, p0 = (tid >> 4) * 4;
  float acc[4][4];
#pragma unroll
  for (int cc = 0; cc < 4; ++cc) {
    float bb = b1[c0 + cc];
#pragma unroll
    for (int pp = 0; pp < 4; ++pp) acc[pp][cc] = bb;
  }
#pragma unroll 4
  for (int j = 0; j < C1; ++j) {
    const float4 f = *(const float4*)&feats[j][p0];
    const float4 wv = *(const float4*)&Wt[j][c0];
    const float fa[4] = {f.x, f.y, f.z, f.w};
    const float wa[4] = {wv.x, wv.y, wv.z, wv.w};
#pragma unroll
    for (int pp = 0; pp < 4; ++pp)
#pragma unroll
      for (int cc = 0; cc < 4; ++cc) acc[pp][cc] = fmaf(fa[pp], wa[cc], acc[pp][cc]);
  }
#pragma unroll
  for (int pp = 0; pp < 4; ++pp) {
    unsigned r0 = pack_bf2(acc[pp][0], acc[pp][1]);
    unsigned r1 = pack_bf2(acc[pp][2], acc[pp][3]);
    unsigned short* dst = (unsigned short*)x1 + (size_t)(m0 + p0 + pp) * 64 + c0;
    *(uint2*)dst = make_uint2(r0, r1);
  }
}

// ---------------- convN: BN(prev)+ReLU on input, then 64 -> COUT conv ----------------
template <int COUT>
__global__ __launch_bounds__(256) void convN_kernel(
    const __hip_bfloat16* __restrict__ xin, const float* __restrict__ stats,
    const float* __restrict__ gamma, const float* __restrict__ beta,
    const float* __restrict__ W, const float* __restrict__ bias,
    __hip_bfloat16* __restrict__ xout) {
  constexpr int CB = COUT / 16;
  __shared__ float feats[64][68];
  __shared__ float Wt[64][COUT];
  __shared__ float scs[64], shs[64];
  const int tid = threadIdx.x;
  const long m0 = (long)blockIdx.x * 64;
  if (tid < 64) {
    float mean = stats[tid] * CNTinv;
    float var = stats[64 + tid] * CNTinv - mean * mean;
    float sc = gamma[tid] * rsqrtf(var + EPSc);
    scs[tid] = sc;
    shs[tid] = beta[tid] - mean * sc;
  }
  for (int e = tid; e < 64 * COUT; e += 256) {
    int c = e >> 6, j = e & 63;
    Wt[j][c] = W[e];
  }
  __syncthreads();
  {
    const int p = tid >> 2, qd = tid & 3;
    const unsigned short* row = (const unsigned short*)xin + (m0 + p) * 64 + qd * 16;
    u16x8 a = *(const u16x8*)row;
    u16x8 bv = *(const u16x8*)(row + 8);
    const int j0 = qd * 16;
#pragma unroll
    for (int u = 0; u < 8; ++u) {
      float f = bf2f(a[u]);
      feats[j0 + u][p] = fmaxf(fmaf(scs[j0 + u], f, shs[j0 + u]), 0.f);
    }
#pragma unroll
    for (int u = 0; u < 8; ++u) {
      float f = bf2f(bv[u]);
      feats[j0 + 8 + u][p] = fmaxf(fmaf(scs[j0 + 8 + u], f, shs[j0 + 8 + u]), 0.f);
    }
  }
  __syncthreads();
  const int c0 = (tid & 15) * CB, p0 = (tid >> 4) * 4;
  float acc[4][CB];
#pragma unroll
  for (int cc = 0; cc < CB; ++cc) {
    float bb = bias[c0 + cc];
#pragma unroll
    for (int pp = 0; pp < 4; ++pp) acc[pp][cc] = bb;
  }
#pragma unroll 4
  for (int j = 0; j < 64; ++j) {
    const float4 f = *(const float4*)&feats[j][p0];
    const float fa[4] = {f.x, f.y, f.z, f.w};
#pragma unroll
    for (int cb = 0; cb < CB; cb += 4) {
      const float4 wv = *(const float4*)&Wt[j][c0 + cb];
      const float wa[4] = {wv.x, wv.y, wv.z, wv.w};
#pragma unroll
      for (int pp = 0; pp < 4; ++pp)
#pragma unroll
        for (int cc = 0; cc < 4; ++cc)
          acc[pp][cb + cc] = fmaf(fa[pp], wa[cc], acc[pp][cb + cc]);
    }
  }
#pragma unroll
  for (int pp = 0; pp < 4; ++pp) {
    unsigned pk[CB / 2];
#pragma unroll
    for (int u = 0; u < CB / 2; ++u) pk[u] = pack_bf2(acc[pp][2 * u], acc[pp][2 * u + 1]);
    unsigned short* dst = (unsigned short*)xout + (m0 + p0 + pp) * COUT + c0;
    if constexpr (CB == 4) {
      *(uint2*)dst = make_uint2(pk[0], pk[1]);
    } else {
      *(uint4*)dst = make_uint4(pk[0], pk[1], pk[2], pk[3]);
    }
  }
}

// ---------------- per-channel sum & sumsq over M rows ----------------
template <int C>
__global__ __launch_bounds__(256) void stats_kernel(const __hip_bfloat16* __restrict__ x,
                                                    float* __restrict__ out) {
  constexpr int G = C / 4;
  const int tid = threadIdx.x;
  const int g = tid % G;
  float s[4] = {0.f, 0.f, 0.f, 0.f}, qq[4] = {0.f, 0.f, 0.f, 0.f};
  const int rstep = (int)gridDim.x * (256 / G);
  for (int r = blockIdx.x * (256 / G) + tid / G; r < Mtot; r += rstep) {
    ushort4 v = *(const ushort4*)((const unsigned short*)x + (size_t)r * C + g * 4);
    float f0 = bf2f(v.x), f1 = bf2f(v.y), f2 = bf2f(v.z), f3 = bf2f(v.w);
    s[0] += f0; qq[0] += f0 * f0;
    s[1] += f1; qq[1] += f1 * f1;
    s[2] += f2; qq[2] += f2 * f2;
    s[3] += f3; qq[3] += f3 * f3;
  }
#pragma unroll
  for (int off = 32; off >= G; off >>= 1) {
#pragma unroll
    for (int u = 0; u < 4; ++u) {
      s[u] += __shfl_xor(s[u], off, 64);
      qq[u] += __shfl_xor(qq[u], off, 64);
    }
  }
  __shared__ float sm[4][G][8];
  const int lane = tid & 63, w = tid >> 6;
  if (lane < G) {
#pragma unroll
    for (int u = 0; u < 4; ++u) {
      sm[w][lane][u] = s[u];
      sm[w][lane][4 + u] = qq[u];
    }
  }
  __syncthreads();
  if (tid < C) {
    float ts = 0.f, tq = 0.f;
#pragma unroll
    for (int w2 = 0; w2 < 4; ++w2) {
      ts += sm[w2][tid >> 2][tid & 3];
      tq += sm[w2][tid >> 2][4 + (tid & 3)];
    }
    atomicAdd(&out[tid], ts);
    atomicAdd(&out[C + tid], tq);
  }
}

// ---------------- BN3 + ReLU + max over K, write [B,128,S] ----------------
__global__ __launch_bounds__(256) void pool_kernel(const __hip_bfloat16* __restrict__ x3,
                                                   const float* __restrict__ stats,
                                                   const float* __restrict__ gamma,
                                                   const float* __restrict__ beta,
                                                   float* __restrict__ out) {
  __shared__ float sc[128], sh[128];
  __shared__ float res[128][33];
  const int tid = threadIdx.x;
  if (tid < 128) {
    float mean = stats[tid] * CNTinv;
    float var = stats[128 + tid] * CNTinv - mean * mean;
    float s = gamma[tid] * rsqrtf(var + EPSc);
    sc[tid] = s;
    sh[tid] = beta[tid] - mean * s;
  }
  __syncthreads();
  const int b = blockIdx.x >> 5;
  const int s0 = (blockIdx.x & 31) * 32;
  const int w = tid >> 6, lane = tid & 63;
  const int c0 = lane * 2;
  const float sc0 = sc[c0], sh0 = sh[c0], sc1 = sc[c0 + 1], sh1 = sh[c0 + 1];
  for (int si = 0; si < 8; ++si) {
    const int s = s0 + w * 8 + si;
    const unsigned* row =
        (const unsigned*)((const unsigned short*)x3 + (size_t)((b * Sc + s) * Kc) * 128) + lane;
    float m0 = -1e30f, m1 = -1e30f;
#pragma unroll 8
    for (int k = 0; k < Kc; ++k) {
      unsigned v = row[k * 64];
      float f0 = bf2f((unsigned short)(v & 0xFFFFu));
      float f1 = bf2f((unsigned short)(v >> 16));
      m0 = fmaxf(m0, fmaxf(fmaf(sc0, f0, sh0), 0.f));
      m1 = fmaxf(m1, fmaxf(fmaf(sc1, f1, sh1), 0.f));
    }
    res[c0][s - s0] = m0;
    res[c0 + 1][s - s0] = m1;
  }
  __syncthreads();
  const int c = tid >> 1, h = tid & 1;
  float* ob = out + (size_t)b * 128 * Sc + (size_t)c * Sc + s0 + h * 16;
#pragma unroll
  for (int u = 0; u < 16; ++u) ob[u] = res[c][h * 16 + u];
}

extern "C" void kernel_launch(void* const* d_in, const int* in_sizes, int n_in,
                              void* d_out, int out_size, void* d_ws, size_t ws_size,
                              hipStream_t stream) {
  const float* xyz = (const float*)d_in[0];
  const float* points = (const float*)d_in[1];
  const float* W1 = (const float*)d_in[2];
  const float* b1 = (const float*)d_in[3];
  const float* g1 = (const float*)d_in[4];
  const float* bt1 = (const float*)d_in[5];
  const float* W2 = (const float*)d_in[6];
  const float* b2 = (const float*)d_in[7];
  const float* g2 = (const float*)d_in[8];
  const float* bt2 = (const float*)d_in[9];
  const float* W3 = (const float*)d_in[10];
  const float* b3 = (const float*)d_in[11];
  const float* g3 = (const float*)d_in[12];
  const float* bt3 = (const float*)d_in[13];
  float* out = (float*)d_out;

  char* ws = (char*)d_ws;
  // layout: fidx[64KB] | idx[2MB] | stats[2KB] | x2[64MB] | x1/x3 alias [128MB]
  int* fidx = (int*)(ws + 0);
  int* idx = (int*)(ws + 65536);
  float* stats = (float*)(ws + 2162688);
  __hip_bfloat16* x2 = (__hip_bfloat16*)(ws + 2164736);
  __hip_bfloat16* x1 = (__hip_bfloat16*)(ws + 2164736 + 67108864);
  __hip_bfloat16* x3 = x1;  // x1 is dead before conv3 writes

  hipMemsetAsync(stats, 0, 512 * sizeof(float), stream);
  fps_kernel<<<Bc, 512, 0, stream>>>(xyz, fidx);
  knn_kernel<<<Bc * Sc / 4, 256, 0, stream>>>(xyz, fidx, out, idx);
  conv1_kernel<<<Mtot / 64, 256, 0, stream>>>(xyz, points, out, idx, W1, b1, x1);
  stats_kernel<64><<<512, 256, 0, stream>>>(x1, stats);
  convN_kernel<64><<<Mtot / 64, 256, 0, stream>>>(x1, stats, g1, bt1, W2, b2, x2);
  stats_kernel<64><<<512, 256, 0, stream>>>(x2, stats + 128);
  convN_kernel<128><<<Mtot / 64, 256, 0, stream>>>(x2, stats + 128, g2, bt2, W3, b3, x3);
  stats_kernel<128><<<512, 256, 0, stream>>>(x3, stats + 256);
  pool_kernel<<<Bc * (Sc / 32), 256, 0, stream>>>(x3, stats + 256, g3, bt3, out + Bc * Sc * 3);
}

// Round 4
// 1487.534 us; speedup vs baseline: 2.0161x; 1.0276x over previous
//
#include <hip/hip_runtime.h>
#include <hip/hip_bf16.h>

typedef __attribute__((ext_vector_type(8))) unsigned short u16x8;

#define DEVI __device__ __forceinline__

constexpr int Bc = 16;
constexpr int Nc = 4096;
constexpr int Sc = 1024;   // NPOINT
constexpr int Kc = 32;
constexpr int Dc = 64;
constexpr int C1 = 67;
constexpr int Mtot = Bc * Sc * Kc;  // 524288
constexpr float EPSc = 1e-5f;
constexpr float CNTinv = 1.0f / (float)Mtot;

// no-FMA squared distance, matches numpy (x*x + y*y) + z*z
DEVI float sqdist3(float dx, float dy, float dz) {
  return __fadd_rn(__fadd_rn(__fmul_rn(dx, dx), __fmul_rn(dy, dy)), __fmul_rn(dz, dz));
}
DEVI unsigned long long umax64(unsigned long long a, unsigned long long b) { return a > b ? a : b; }
DEVI float bf2f(unsigned short u) { return __uint_as_float(((unsigned)u) << 16); }
DEVI unsigned pack_bf2(float a, float b) {
  __hip_bfloat16 ha = __float2bfloat16(a), hb = __float2bfloat16(b);
  unsigned short ua, ub;
  __builtin_memcpy(&ua, &ha, 2);
  __builtin_memcpy(&ub, &hb, 2);
  return (unsigned)ua | ((unsigned)ub << 16);
}

// ---- wave64 DPP reductions: result broadcast via readlane(63) ----
#define DPP_STAGE(v, OP, CTRL, MASK)                                                       \
  {                                                                                        \
    int _t = __builtin_amdgcn_update_dpp(__float_as_int(v), __float_as_int(v), CTRL, MASK, \
                                         0xF, false);                                      \
    v = OP(v, __int_as_float(_t));                                                         \
  }
DEVI float wave_fmax63(float v) {
  DPP_STAGE(v, fmaxf, 0xB1, 0xF)
  DPP_STAGE(v, fmaxf, 0x4E, 0xF)
  DPP_STAGE(v, fmaxf, 0x141, 0xF)
  DPP_STAGE(v, fmaxf, 0x140, 0xF)
  DPP_STAGE(v, fmaxf, 0x142, 0xA)
  DPP_STAGE(v, fmaxf, 0x143, 0xC)
  return __int_as_float(__builtin_amdgcn_readlane(__float_as_int(v), 63));
}
DEVI float wave_fmin63(float v) {
  DPP_STAGE(v, fminf, 0xB1, 0xF)
  DPP_STAGE(v, fminf, 0x4E, 0xF)
  DPP_STAGE(v, fminf, 0x141, 0xF)
  DPP_STAGE(v, fminf, 0x140, 0xF)
  DPP_STAGE(v, fminf, 0x142, 0xA)
  DPP_STAGE(v, fminf, 0x143, 0xC)
  return __int_as_float(__builtin_amdgcn_readlane(__float_as_int(v), 63));
}
#define DPP_STAGE_U(v, CTRL, MASK)                                                      \
  {                                                                                     \
    unsigned _t = (unsigned)__builtin_amdgcn_update_dpp((int)(v), (int)(v), CTRL, MASK, \
                                                        0xF, false);                    \
    v = (_t < v) ? _t : v;                                                              \
  }
DEVI unsigned wave_umin63(unsigned v) {
  DPP_STAGE_U(v, 0xB1, 0xF)
  DPP_STAGE_U(v, 0x4E, 0xF)
  DPP_STAGE_U(v, 0x141, 0xF)
  DPP_STAGE_U(v, 0x140, 0xF)
  DPP_STAGE_U(v, 0x142, 0xA)
  DPP_STAGE_U(v, 0x143, 0xC)
  return (unsigned)__builtin_amdgcn_readlane((int)v, 63);
}

// ---------------- FPS: 256 thr (4 waves), ballot+readlane winner, 1 barrier/step ----------------
__global__ __launch_bounds__(256) void fps_kernel(const float* __restrict__ xyz,
                                                  int* __restrict__ fidx) {
  __shared__ float4 lsc[Nc];  // 64 KiB coord table (read-only in loop)
  __shared__ __align__(16) unsigned long long wkey[2][4];
  __shared__ int sidx[Sc];
  const int b = blockIdx.x;
  const float* xb = xyz + (size_t)b * Nc * 3;
  const int tid = threadIdx.x;
  const int lane = tid & 63, w = tid >> 6;

  float px[16], py[16], pz[16], dist[16];
#pragma unroll
  for (int i = 0; i < 16; ++i) {
    int p = tid + i * 256;
    px[i] = xb[p * 3 + 0];
    py[i] = xb[p * 3 + 1];
    pz[i] = xb[p * 3 + 2];
    dist[i] = 1e10f;
  }
  for (int e = tid; e < Nc; e += 256)
    lsc[e] = make_float4(xb[e * 3 + 0], xb[e * 3 + 1], xb[e * 3 + 2], 0.f);
  if (tid == 0) sidx[0] = 0;
  __syncthreads();

  int widx = 0;
  for (int t = 1; t < Sc; ++t) {
    const float4 c = lsc[widx];
    float nd[16];
#pragma unroll
    for (int i = 0; i < 16; ++i) {
      float d = sqdist3(px[i] - c.x, py[i] - c.y, pz[i] - c.z);
      float v = fminf(dist[i], d);
      dist[i] = v;
      nd[i] = v;
    }
    // depth-4 tree max over this lane's 16 updated distances
    float t8[8], t4[4];
#pragma unroll
    for (int u = 0; u < 8; ++u) t8[u] = fmaxf(nd[u], nd[u + 8]);
#pragma unroll
    for (int u = 0; u < 4; ++u) t4[u] = fmaxf(t8[u], t8[u + 4]);
    const float mymax = fmaxf(fmaxf(t4[0], t4[1]), fmaxf(t4[2], t4[3]));
    const float maxw = wave_fmax63(mymax);  // wave max, broadcast
    // smallest local point index with nd == maxw (reverse scan -> smallest i wins)
    unsigned lp = 0xFFFFFFFFu;
#pragma unroll
    for (int i = 15; i >= 0; --i) lp = (nd[i] == maxw) ? (unsigned)(tid + (i << 8)) : lp;
    const unsigned long long mask = __ballot(mymax == maxw);
    unsigned wavep;
    if (__builtin_popcountll(mask) == 1) {
      wavep = (unsigned)__builtin_amdgcn_readlane((int)lp, (int)__builtin_ctzll(mask));
    } else {
      wavep = wave_umin63(lp);  // exact smallest-index tie-break (rare)
    }
    if (lane == 0)
      wkey[t & 1][w] = ((unsigned long long)__float_as_uint(maxw) << 32) |
                       (unsigned long long)(0xFFFFFFFFu - wavep);
    __syncthreads();
    const ulonglong2* wp = (const ulonglong2*)wkey[t & 1];
    ulonglong2 a0 = wp[0], a1 = wp[1];
    unsigned long long m = umax64(umax64(a0.x, a0.y), umax64(a1.x, a1.y));
    widx = (int)(0xFFFFFFFFu - (unsigned)(m & 0xFFFFFFFFu));
    if (tid == 0) sidx[t] = widx;
  }
  __syncthreads();
  for (int e = tid; e < Sc; e += 256) fidx[b * Sc + e] = sidx[e];
}

// ---------------- kNN: one wave/query, top-2 cache + taken mask, ballot argmin ----------------
__global__ __launch_bounds__(256) void knn_kernel(const float* __restrict__ xyz,
                                                  const int* __restrict__ fidx,
                                                  float* __restrict__ new_xyz,
                                                  int* __restrict__ idx) {
  const int w = threadIdx.x >> 6;
  const int lane = threadIdx.x & 63;
  const int q = blockIdx.x * 4 + w;
  const int b = q >> 10;
  const int s = q & (Sc - 1);
  const float* xb = xyz + (size_t)b * Nc * 3;
  const int ci = fidx[b * Sc + s];
  const float cx = xb[ci * 3 + 0], cy = xb[ci * 3 + 1], cz = xb[ci * 3 + 2];
  if (lane == 0) {
    new_xyz[(b * Sc + s) * 3 + 0] = cx;
    new_xyz[(b * Sc + s) * 3 + 1] = cy;
    new_xyz[(b * Sc + s) * 3 + 2] = cz;
  }
  const float INF = __int_as_float(0x7F800000);
  // lane owns points p = lane + 64*i, i in [0,64)
  const float* pp = xb + lane * 3;
  float d0 = INF, d1 = INF;
  int i0 = 0, i1 = 0;
#pragma unroll 4
  for (int i = 0; i < 64; ++i) {
    const float x = pp[i * 192 + 0], y = pp[i * 192 + 1], z = pp[i * 192 + 2];
    const float d = sqdist3(x - cx, y - cy, z - cz);
    const bool c0 = d < d0, c1 = d < d1;  // strict <: stable (earlier i kept on ties)
    d1 = c0 ? d0 : (c1 ? d : d1);
    i1 = c0 ? i0 : (c1 ? i : i1);
    d0 = c0 ? d : d0;
    i0 = c0 ? i : i0;
  }
  unsigned long long taken = 0ull;
  int* outp = idx + ((size_t)b * Sc + s) * Kc;
#pragma unroll 1
  for (int r = 0; r < Kc; ++r) {
    const float mind = wave_fmin63(d0);
    const unsigned myp = (unsigned)(lane + (i0 << 6));
    const unsigned long long mask = __ballot(d0 == mind);
    unsigned W;
    if (__builtin_popcountll(mask) == 1) {
      W = (unsigned)__builtin_amdgcn_readlane((int)myp, (int)__builtin_ctzll(mask));
    } else {
      unsigned c = (d0 == mind) ? myp : 0xFFFFFFFFu;
      W = wave_umin63(c);  // exact (dist, idx) lexicographic argmin (rare)
    }
    if (lane == 0) outp[r] = (int)W;
    if (myp == W) {  // unique winner lane (lane = W & 63)
      taken |= (1ull << i0);
      d0 = d1;
      i0 = i1;
      d1 = INF;
      if (__float_as_uint(d0) == 0x7F800000u) {  // cache exhausted -> rebuild top-2
        float e0 = INF, e1 = INF;
        int j0 = 0, j1 = 0;
#pragma unroll 4
        for (int i = 0; i < 64; ++i) {
          const float x = pp[i * 192 + 0], y = pp[i * 192 + 1], z = pp[i * 192 + 2];
          float d = sqdist3(x - cx, y - cy, z - cz);
          d = ((taken >> i) & 1ull) ? INF : d;
          const bool c0b = d < e0, c1b = d < e1;
          e1 = c0b ? e0 : (c1b ? d : e1);
          j1 = c0b ? j0 : (c1b ? i : j1);
          e0 = c0b ? d : e0;
          j0 = c0b ? i : j0;
        }
        d0 = e0; i0 = j0; d1 = e1; i1 = j1;
      }
    }
  }
}

// ---------------- conv1: gather (3 xyz-diff + 64 point feats) -> 64 channels ----------------
__global__ __launch_bounds__(256) void conv1_kernel(
    const float* __restrict__ xyz, const float* __restrict__ points,
    const float* __restrict__ new_xyz, const int* __restrict__ idx,
    const float* __restrict__ W1, const float* __restrict__ b1,
    __hip_bfloat16* __restrict__ x1) {
  __shared__ float feats[C1][68];
  __shared__ float Wt[C1][64];
  const int tid = threadIdx.x;
  const int m0 = blockIdx.x * 64;
  for (int e = tid; e < 64 * C1; e += 256) {
    int c = e / C1, j = e % C1;
    Wt[j][c] = W1[e];
  }
  {
    const int p = tid >> 2, qd = tid & 3;
    const int m = m0 + p;
    const int b = m >> 15;             // /(S*K)
    const int s = (m >> 5) & (Sc - 1); // (m/K)%S
    const int i = idx[m];
    const float* pr = points + ((size_t)b * Nc + i) * Dc + qd * 16;
    float4 v0 = *(const float4*)(pr + 0);
    float4 v1 = *(const float4*)(pr + 4);
    float4 v2 = *(const float4*)(pr + 8);
    float4 v3 = *(const float4*)(pr + 12);
    float vv[16] = {v0.x, v0.y, v0.z, v0.w, v1.x, v1.y, v1.z, v1.w,
                    v2.x, v2.y, v2.z, v2.w, v3.x, v3.y, v3.z, v3.w};
    const int j0 = 3 + qd * 16;
#pragma unroll
    for (int u = 0; u < 16; ++u) feats[j0 + u][p] = vv[u];
    if (qd == 0) {
      const float* xp = xyz + ((size_t)b * Nc + i) * 3;
      const float* cp = new_xyz + ((size_t)b * Sc + s) * 3;
      feats[0][p] = xp[0] - cp[0];
      feats[1][p] = xp[1] - cp[1];
      feats[2][p] = xp[2] - cp[2];
    }
  }
  __syncthreads();
  const int c0 = (tid & 15) * 4, p0 = (tid >> 4) * 4;
  float acc[4][4];
#pragma unroll
  for (int cc = 0; cc < 4; ++cc) {
    float bb = b1[c0 + cc];
#pragma unroll
    for (int pp = 0; pp < 4; ++pp) acc[pp][cc] = bb;
  }
#pragma unroll 4
  for (int j = 0; j < C1; ++j) {
    const float4 f = *(const float4*)&feats[j][p0];
    const float4 wv = *(const float4*)&Wt[j][c0];
    const float fa[4] = {f.x, f.y, f.z, f.w};
    const float wa[4] = {wv.x, wv.y, wv.z, wv.w};
#pragma unroll
    for (int pp = 0; pp < 4; ++pp)
#pragma unroll
      for (int cc = 0; cc < 4; ++cc) acc[pp][cc] = fmaf(fa[pp], wa[cc], acc[pp][cc]);
  }
#pragma unroll
  for (int pp = 0; pp < 4; ++pp) {
    unsigned r0 = pack_bf2(acc[pp][0], acc[pp][1]);
    unsigned r1 = pack_bf2(acc[pp][2], acc[pp][3]);
    unsigned short* dst = (unsigned short*)x1 + (size_t)(m0 + p0 + pp) * 64 + c0;
    *(uint2*)dst = make_uint2(r0, r1);
  }
}

// ---------------- convN: BN(prev)+ReLU on input, then 64 -> COUT conv ----------------
template <int COUT>
__global__ __launch_bounds__(256) void convN_kernel(
    const __hip_bfloat16* __restrict__ xin, const float* __restrict__ stats,
    const float* __restrict__ gamma, const float* __restrict__ beta,
    const float* __restrict__ W, const float* __restrict__ bias,
    __hip_bfloat16* __restrict__ xout) {
  constexpr int CB = COUT / 16;
  __shared__ float feats[64][68];
  __shared__ float Wt[64][COUT];
  __shared__ float scs[64], shs[64];
  const int tid = threadIdx.x;
  const long m0 = (long)blockIdx.x * 64;
  if (tid < 64) {
    float mean = stats[tid] * CNTinv;
    float var = stats[64 + tid] * CNTinv - mean * mean;
    float sc = gamma[tid] * rsqrtf(var + EPSc);
    scs[tid] = sc;
    shs[tid] = beta[tid] - mean * sc;
  }
  for (int e = tid; e < 64 * COUT; e += 256) {
    int c = e >> 6, j = e & 63;
    Wt[j][c] = W[e];
  }
  __syncthreads();
  {
    const int p = tid >> 2, qd = tid & 3;
    const unsigned short* row = (const unsigned short*)xin + (m0 + p) * 64 + qd * 16;
    u16x8 a = *(const u16x8*)row;
    u16x8 bv = *(const u16x8*)(row + 8);
    const int j0 = qd * 16;
#pragma unroll
    for (int u = 0; u < 8; ++u) {
      float f = bf2f(a[u]);
      feats[j0 + u][p] = fmaxf(fmaf(scs[j0 + u], f, shs[j0 + u]), 0.f);
    }
#pragma unroll
    for (int u = 0; u < 8; ++u) {
      float f = bf2f(bv[u]);
      feats[j0 + 8 + u][p] = fmaxf(fmaf(scs[j0 + 8 + u], f, shs[j0 + 8 + u]), 0.f);
    }
  }
  __syncthreads();
  const int c0 = (tid & 15) * CB, p0 = (tid >> 4) * 4;
  float acc[4][CB];
#pragma unroll
  for (int cc = 0; cc < CB; ++cc) {
    float bb = bias[c0 + cc];
#pragma unroll
    for (int pp = 0; pp < 4; ++pp) acc[pp][cc] = bb;
  }
#pragma unroll 4
  for (int j = 0; j < 64; ++j) {
    const float4 f = *(const float4*)&feats[j][p0];
    const float fa[4] = {f.x, f.y, f.z, f.w};
#pragma unroll
    for (int cb = 0; cb < CB; cb += 4) {
      const float4 wv = *(const float4*)&Wt[j][c0 + cb];
      const float wa[4] = {wv.x, wv.y, wv.z, wv.w};
#pragma unroll
      for (int pp = 0; pp < 4; ++pp)
#pragma unroll
        for (int cc = 0; cc < 4; ++cc)
          acc[pp][cb + cc] = fmaf(fa[pp], wa[cc], acc[pp][cb + cc]);
    }
  }
#pragma unroll
  for (int pp = 0; pp < 4; ++pp) {
    unsigned pk[CB / 2];
#pragma unroll
    for (int u = 0; u < CB / 2; ++u) pk[u] = pack_bf2(acc[pp][2 * u], acc[pp][2 * u + 1]);
    unsigned short* dst = (unsigned short*)xout + (m0 + p0 + pp) * COUT + c0;
    if constexpr (CB == 4) {
      *(uint2*)dst = make_uint2(pk[0], pk[1]);
    } else {
      *(uint4*)dst = make_uint4(pk[0], pk[1], pk[2], pk[3]);
    }
  }
}

// ---------------- per-channel sum & sumsq over M rows ----------------
template <int C>
__global__ __launch_bounds__(256) void stats_kernel(const __hip_bfloat16* __restrict__ x,
                                                    float* __restrict__ out) {
  constexpr int G = C / 4;
  const int tid = threadIdx.x;
  const int g = tid % G;
  float s[4] = {0.f, 0.f, 0.f, 0.f}, qq[4] = {0.f, 0.f, 0.f, 0.f};
  const int rstep = (int)gridDim.x * (256 / G);
  for (int r = blockIdx.x * (256 / G) + tid / G; r < Mtot; r += rstep) {
    ushort4 v = *(const ushort4*)((const unsigned short*)x + (size_t)r * C + g * 4);
    float f0 = bf2f(v.x), f1 = bf2f(v.y), f2 = bf2f(v.z), f3 = bf2f(v.w);
    s[0] += f0; qq[0] += f0 * f0;
    s[1] += f1; qq[1] += f1 * f1;
    s[2] += f2; qq[2] += f2 * f2;
    s[3] += f3; qq[3] += f3 * f3;
  }
#pragma unroll
  for (int off = 32; off >= G; off >>= 1) {
#pragma unroll
    for (int u = 0; u < 4; ++u) {
      s[u] += __shfl_xor(s[u], off, 64);
      qq[u] += __shfl_xor(qq[u], off, 64);
    }
  }
  __shared__ float sm[4][G][8];
  const int lane = tid & 63, w = tid >> 6;
  if (lane < G) {
#pragma unroll
    for (int u = 0; u < 4; ++u) {
      sm[w][lane][u] = s[u];
      sm[w][lane][4 + u] = qq[u];
    }
  }
  __syncthreads();
  if (tid < C) {
    float ts = 0.f, tq = 0.f;
#pragma unroll
    for (int w2 = 0; w2 < 4; ++w2) {
      ts += sm[w2][tid >> 2][tid & 3];
      tq += sm[w2][tid >> 2][4 + (tid & 3)];
    }
    atomicAdd(&out[tid], ts);
    atomicAdd(&out[C + tid], tq);
  }
}

// ---------------- BN3 + ReLU + max over K, write [B,128,S] ----------------
__global__ __launch_bounds__(256) void pool_kernel(const __hip_bfloat16* __restrict__ x3,
                                                   const float* __restrict__ stats,
                                                   const float* __restrict__ gamma,
                                                   const float* __restrict__ beta,
                                                   float* __restrict__ out) {
  __shared__ float sc[128], sh[128];
  __shared__ float res[128][33];
  const int tid = threadIdx.x;
  if (tid < 128) {
    float mean = stats[tid] * CNTinv;
    float var = stats[128 + tid] * CNTinv - mean * mean;
    float s = gamma[tid] * rsqrtf(var + EPSc);
    sc[tid] = s;
    sh[tid] = beta[tid] - mean * s;
  }
  __syncthreads();
  const int b = blockIdx.x >> 5;
  const int s0 = (blockIdx.x & 31) * 32;
  const int w = tid >> 6, lane = tid & 63;
  const int c0 = lane * 2;
  const float sc0 = sc[c0], sh0 = sh[c0], sc1 = sc[c0 + 1], sh1 = sh[c0 + 1];
  for (int si = 0; si < 8; ++si) {
    const int s = s0 + w * 8 + si;
    const unsigned* row =
        (const unsigned*)((const unsigned short*)x3 + (size_t)((b * Sc + s) * Kc) * 128) + lane;
    float m0 = -1e30f, m1 = -1e30f;
#pragma unroll 8
    for (int k = 0; k < Kc; ++k) {
      unsigned v = row[k * 64];
      float f0 = bf2f((unsigned short)(v & 0xFFFFu));
      float f1 = bf2f((unsigned short)(v >> 16));
      m0 = fmaxf(m0, fmaxf(fmaf(sc0, f0, sh0), 0.f));
      m1 = fmaxf(m1, fmaxf(fmaf(sc1, f1, sh1), 0.f));
    }
    res[c0][s - s0] = m0;
    res[c0 + 1][s - s0] = m1;
  }
  __syncthreads();
  const int c = tid >> 1, h = tid & 1;
  float* ob = out + (size_t)b * 128 * Sc + (size_t)c * Sc + s0 + h * 16;
#pragma unroll
  for (int u = 0; u < 16; ++u) ob[u] = res[c][h * 16 + u];
}

extern "C" void kernel_launch(void* const* d_in, const int* in_sizes, int n_in,
                              void* d_out, int out_size, void* d_ws, size_t ws_size,
                              hipStream_t stream) {
  const float* xyz = (const float*)d_in[0];
  const float* points = (const float*)d_in[1];
  const float* W1 = (const float*)d_in[2];
  const float* b1 = (const float*)d_in[3];
  const float* g1 = (const float*)d_in[4];
  const float* bt1 = (const float*)d_in[5];
  const float* W2 = (const float*)d_in[6];
  const float* b2 = (const float*)d_in[7];
  const float* g2 = (const float*)d_in[8];
  const float* bt2 = (const float*)d_in[9];
  const float* W3 = (const float*)d_in[10];
  const float* b3 = (const float*)d_in[11];
  const float* g3 = (const float*)d_in[12];
  const float* bt3 = (const float*)d_in[13];
  float* out = (float*)d_out;

  char* ws = (char*)d_ws;
  // layout: fidx[64KB] | idx[2MB] | stats[2KB] | x2[64MB] | x1/x3 alias [128MB]
  int* fidx = (int*)(ws + 0);
  int* idx = (int*)(ws + 65536);
  float* stats = (float*)(ws + 2162688);
  __hip_bfloat16* x2 = (__hip_bfloat16*)(ws + 2164736);
  __hip_bfloat16* x1 = (__hip_bfloat16*)(ws + 2164736 + 67108864);
  __hip_bfloat16* x3 = x1;  // x1 is dead before conv3 writes

  hipMemsetAsync(stats, 0, 512 * sizeof(float), stream);
  fps_kernel<<<Bc, 256, 0, stream>>>(xyz, fidx);
  knn_kernel<<<Bc * Sc / 4, 256, 0, stream>>>(xyz, fidx, out, idx);
  conv1_kernel<<<Mtot / 64, 256, 0, stream>>>(xyz, points, out, idx, W1, b1, x1);
  stats_kernel<64><<<512, 256, 0, stream>>>(x1, stats);
  convN_kernel<64><<<Mtot / 64, 256, 0, stream>>>(x1, stats, g1, bt1, W2, b2, x2);
  stats_kernel<64><<<512, 256, 0, stream>>>(x2, stats + 128);
  convN_kernel<128><<<Mtot / 64, 256, 0, stream>>>(x2, stats + 128, g2, bt2, W3, b3, x3);
  stats_kernel<128><<<512, 256, 0, stream>>>(x3, stats + 256);
  pool_kernel<<<Bc * (Sc / 32), 256, 0, stream>>>(x3, stats + 256, g3, bt3, out + Bc * Sc * 3);
}